// Round 9
// baseline (453.418 us; speedup 1.0000x reference)
//
#include <hip/hip_runtime.h>
#include <hip/hip_bf16.h>
#include <hip/hip_cooperative_groups.h>
#include <math.h>

namespace cg = cooperative_groups;

typedef __attribute__((ext_vector_type(8))) short bf16x8;
typedef __attribute__((ext_vector_type(4))) float f32x4;

#define SEQ 1024
#define DIM 768
#define NH 12
#define HD 64
#define NBLK 400

// ws BYTE offsets:
#define OFF_QB   0
#define OFF_KB   1572864
#define OFF_VT   3145728
#define OFF_OPRE 4718592
#define OFF_G    6291456
#define OFF_SCAL 6438912
#define OFF_XB   6684672
#define OFF_WQB  8257536
#define OFF_WKB  9437184
#define OFF_WVB  10616832
#define OFF_WUB  11796480
#define OFF_WGB  12976128
#define OFF_WOB  13031424
#define OFF_PSUM 14211072

__device__ __forceinline__ float wave_reduce_sum(float v) {
    for (int off = 1; off < 64; off <<= 1) v += __shfl_xor(v, off);
    return v;
}
__device__ __forceinline__ float wave_reduce_max(float v) {
    for (int off = 1; off < 64; off <<= 1) v = fmaxf(v, __shfl_xor(v, off));
    return v;
}
__device__ __forceinline__ short f2bs(float x) {
    __hip_bfloat16 h = __float2bfloat16(x);
    return *reinterpret_cast<short*>(&h);
}
__device__ __forceinline__ float bs2f(short x) {
    __hip_bfloat16 h = *reinterpret_cast<__hip_bfloat16*>(&x);
    return (float)h;
}
__device__ __forceinline__ bf16x8 cvt8r(const float4& a, const float4& b) {
    bf16x8 r;
    r[0]=f2bs(a.x); r[1]=f2bs(a.y); r[2]=f2bs(a.z); r[3]=f2bs(a.w);
    r[4]=f2bs(b.x); r[5]=f2bs(b.y); r[6]=f2bs(b.z); r[7]=f2bs(b.w);
    return r;
}
__device__ __forceinline__ void async_copy16(const void* gptr, void* ldsbase, int lane) {
#if __has_builtin(__builtin_amdgcn_global_load_lds)
    __builtin_amdgcn_global_load_lds(
        (const __attribute__((address_space(1))) unsigned int*)gptr,
        (__attribute__((address_space(3))) unsigned int*)ldsbase, 16, 0, 0);
#else
    *(bf16x8*)((short*)ldsbase + lane*8) = *(const bf16x8*)gptr;
#endif
}

__global__ __launch_bounds__(256, 2) void k_fused(
    const float* __restrict__ X,  const float* __restrict__ Wq,
    const float* __restrict__ Wk, const float* __restrict__ Wv,
    const float* __restrict__ Wu, const float* __restrict__ Wg,
    const float* __restrict__ Wo, const float* __restrict__ pmu,
    const float* __restrict__ plt, char* __restrict__ ws, void* __restrict__ dout)
{
    cg::grid_group grid = cg::this_grid();
    alignas(16) __shared__ char smem[49152];

    int bid = blockIdx.x, tid = threadIdx.x;
    int wv = tid >> 6, lane = tid & 63, g = lane >> 4, n = lane & 15;

    __hip_bfloat16* Qb   = (__hip_bfloat16*)(ws + OFF_QB);
    __hip_bfloat16* Kb   = (__hip_bfloat16*)(ws + OFF_KB);
    __hip_bfloat16* Vt   = (__hip_bfloat16*)(ws + OFF_VT);
    __hip_bfloat16* opre = (__hip_bfloat16*)(ws + OFF_OPRE);
    float* Gt  = (float*)(ws + OFF_G);
    float* si_ = (float*)(ws + OFF_SCAL);
    float* es_ = si_ + NH*SEQ;
    float* al_ = es_ + NH*SEQ;
    float* be_ = al_ + NH*SEQ;
    float* ga_ = be_ + NH*SEQ;
    short* Xb  = (short*)(ws + OFF_XB);
    short* Wqb = (short*)(ws + OFF_WQB);
    short* Wkb = (short*)(ws + OFF_WKB);
    short* Wvb = (short*)(ws + OFF_WVB);
    short* Wub = (short*)(ws + OFF_WUB);
    short* Wgb = (short*)(ws + OFF_WGB);
    short* Wob = (short*)(ws + OFF_WOB);
    float* Psum = (float*)(ws + OFF_PSUM);
    __hip_bfloat16* Ub = (__hip_bfloat16*)dout;   // u scratch; P4 overwrites
    float* out = (float*)dout;

    // ================= P0: cast inputs to bf16 =================
    for (int idx = bid*256 + tid; idx < 470400; idx += NBLK*256) {
        const float* src; short* dst; int off;
        if      (idx < 98304)  { src = X;  dst = Xb;  off = idx; }
        else if (idx < 172032) { src = Wq; dst = Wqb; off = idx - 98304; }
        else if (idx < 245760) { src = Wk; dst = Wkb; off = idx - 172032; }
        else if (idx < 319488) { src = Wv; dst = Wvb; off = idx - 245760; }
        else if (idx < 393216) { src = Wu; dst = Wub; off = idx - 319488; }
        else if (idx < 396672) { src = Wg; dst = Wgb; off = idx - 393216; }
        else                   { src = Wo; dst = Wob; off = idx - 396672; }
        const float* s = src + (size_t)off*8;
        *(bf16x8*)(dst + (size_t)off*8) = cvt8r(*(const float4*)s, *(const float4*)(s + 4));
    }
    grid.sync();

    // ================= P1: projections (task = bid, 400 tasks) =================
    {
        int t = bid;
        int mat, rt, ct;
        if (t < 288)      { int m3 = t/96; mat = (m3==2)?3:m3; int r = t%96; rt = r/6; ct = r%6; }
        else if (t < 384) { mat = 2; int r = t-288; rt = r/8; ct = r%8; }
        else              { mat = 4; rt = t-384; ct = 0; }

        short* lds = (short*)smem;   // A dbuf @0/4096 (64x64), B dbuf @8192/16384 (128x64)
        int wn = wv;

        const short* Asrc; const short* Bsrc; int arow0, brow0, Brows;
        if (mat == 2) { Asrc = Wvb; Bsrc = Xb; arow0 = rt*64; brow0 = ct*128; Brows = SEQ; }
        else {
            Asrc = Xb; arow0 = rt*64; brow0 = ct*128;
            Bsrc = (mat==0)?Wqb:(mat==1)?Wkb:(mat==3)?Wub:Wgb;
            Brows = (mat==4) ? 36 : DIM;
        }

        auto dma_step = [&](int buf, int k0) {
            short* Ab = lds + buf*4096;
            short* Bb = lds + 8192 + buf*8192;
            for (int p = 0; p < 2; ++p) {
                int sbase = p*256 + wv*64;
                int s = sbase + lane;
                int r = s >> 3, c = s & 7, cl = c ^ (r & 7);
                async_copy16(Asrc + (size_t)(arow0 + r)*DIM + k0 + cl*8, Ab + sbase*8, lane);
            }
            for (int p = 0; p < 4; ++p) {
                int sbase = p*256 + wv*64;
                int s = sbase + lane;
                int r = s >> 3, c = s & 7, cl = c ^ (r & 7);
                int gr = brow0 + r; if (gr >= Brows) gr = Brows - 1;
                async_copy16(Bsrc + (size_t)gr*DIM + k0 + cl*8, Bb + sbase*8, lane);
            }
        };

        f32x4 acc[4][2];
        for (int i=0;i<4;++i) for (int j=0;j<2;++j) acc[i][j] = (f32x4){0,0,0,0};

        dma_step(0, 0);
        for (int it = 0; it < 12; ++it) {
            __syncthreads();
            if (it < 11) dma_step(1 - (it & 1), (it + 1)*64);
            int buf = it & 1;
            const short* Ab = lds + buf*4096;
            const short* Bb = lds + 8192 + buf*8192;
            for (int ks = 0; ks < 2; ++ks) {
                int q = ks*4 + g;
                bf16x8 af[4], bfr[2];
                for (int i=0;i<4;++i)
                    af[i] = *(const bf16x8*)(&Ab[((i*16+n)*8 + (q ^ (n&7)))*8]);
                for (int j=0;j<2;++j)
                    bfr[j] = *(const bf16x8*)(&Bb[((wn*32+j*16+n)*8 + (q ^ (n&7)))*8]);
                for (int i=0;i<4;++i)
                    for (int j=0;j<2;++j)
                        acc[i][j] = __builtin_amdgcn_mfma_f32_16x16x32_bf16(af[i], bfr[j], acc[i][j], 0,0,0);
            }
        }
        __syncthreads();

        if (mat == 4) {
            for (int i=0;i<4;++i) for (int j=0;j<2;++j) for (int r=0;r<4;++r) {
                int row = rt*64 + i*16 + g*4 + r;
                int col = wn*32 + j*16 + n;
                if (col < 36) Gt[(size_t)row*36 + col] = acc[i][j][r];
            }
        } else {
            short* C = lds;
            for (int i=0;i<4;++i) for (int j=0;j<2;++j) for (int r=0;r<4;++r)
                C[(i*16 + g*4 + r)*128 + wn*32 + j*16 + n] = f2bs(acc[i][j][r]);
            __syncthreads();

            if (mat == 2) {
                for (int k = 0; k < 16; ++k) {
                    int row = k*4 + wv;
                    unsigned int v = ((const unsigned int*)C)[row*64 + lane];
                    ((unsigned int*)(Vt + (size_t)(rt*64 + row)*SEQ + ct*128))[lane] = v;
                }
            } else if (mat == 3) {
                for (int k = 0; k < 32; ++k) {
                    int u = k*4 + wv;
                    int row = u >> 1, hsel = u & 1;
                    Ub[((size_t)(2*ct + hsel)*SEQ + rt*64 + row)*HD + lane] =
                        *(__hip_bfloat16*)&C[row*128 + hsel*64 + lane];
                }
            } else {
                __hip_bfloat16* dst = (mat==0) ? Qb : Kb;
                int i2 = lane >> 1;
                float inv = expf((float)i2 * (-9.210340371976184f / 32.f));
                for (int k = 0; k < 32; ++k) {
                    int u = k*4 + wv;
                    int row = u >> 1, hsel = u & 1;
                    int l = rt*64 + row;
                    float x = bs2f(C[row*128 + hsel*64 + lane]);
                    float ang = (float)l * inv;
                    float c = cosf(ang), s = sinf(ang);
                    float p = __shfl(x, lane ^ 32);
                    float rot = (lane < 32) ? -p : p;
                    float y = x*c + rot*s;
                    float nrm = wave_reduce_sum(y*y);
                    y = y / fmaxf(sqrtf(nrm), 1e-12f);
                    dst[((size_t)(2*ct + hsel)*SEQ + l)*HD + lane] = __float2bfloat16(y);
                }
            }
        }
    }
    grid.sync();

    // ================= P2a: per-(h,chunk) partial sums of u =================
    if (bid < 48) {
        int t = bid*4 + wv;                 // 0..191
        int h = t >> 4, chunk = t & 15;
        const __hip_bfloat16* up = Ub + ((size_t)h*SEQ + chunk*64)*HD + lane;
        float s = 0.f;
        for (int i = 0; i < 64; ++i) s += (float)up[(size_t)i*HD];
        Psum[((size_t)h*16 + chunk)*64 + lane] = s;
    }
    grid.sync();

    // ================= P2b: per-(h,chunk) serial s_i =================
    if (bid < 48) {
        int t = bid*4 + wv;
        int h = t >> 4, chunk = t & 15;
        float ltv = fminf(fmaxf(plt[h], -50.f), 30.f);
        float ltau = expf(ltv);
        float mu = pmu[h*HD + lane];
        float V = ltau * mu;
        for (int c = 0; c < chunk; ++c) V += Psum[((size_t)h*16 + c)*64 + lane];
        const __hip_bfloat16* up = Ub + ((size_t)h*SEQ + chunk*64)*HD + lane;
        for (int i = 0; i < 64; ++i) {
            float uv = (float)up[(size_t)i*HD];
            V += uv;
            int l = chunk*64 + i;
            float bar = V / (ltau + (float)(l + 1));
            float p = wave_reduce_sum(uv * bar);
            if (lane == 0) si_[h*SEQ + l] = -p * 0.125f;   // / sqrt(64)
        }
    }
    grid.sync();

    // ================= P2c: per-head smax + E/P scans + alpha/beta/gamma ========
    if (bid < NH) {
        int h = bid;
        float* sb = (float*)smem;
        float* eb = sb + 1024;
        float* g1 = eb + 1024;
        float* gh = g1 + 1024;
        float* redu = gh + 1024;
        float vmax = -1e30f;
        for (int r = 0; r < 4; ++r) {
            int l = r*256 + tid;
            float v = si_[h*SEQ + l];
            sb[l] = v;
            vmax = fmaxf(vmax, v);
        }
        vmax = wave_reduce_max(vmax);
        if (lane == 0) redu[wv] = vmax;
        __syncthreads();
        float smax = fmaxf(fmaxf(redu[0], redu[1]), fmaxf(redu[2], redu[3]));
        for (int r = 0; r < 4; ++r) {
            int l = r*256 + tid;
            float ev = expf(fminf(sb[l] - smax, 0.f));
            eb[l] = ev;
            es_[h*SEQ + l] = ev;
            g1[l] = 1.f / (1.f + expf(-Gt[(size_t)l*36 + h*3 + 0]));
            gh[l] = 1.f / (1.f + expf(-Gt[(size_t)l*36 + h*3 + 1]));
        }
        __syncthreads();
        if (wv == 0) {
            int base = lane * 16;
            float se = 0.f, ss = 0.f;
            for (int i = 0; i < 16; ++i) { se += eb[base + i]; ss += sb[base + i]; }
            float pe = se, ps = ss;
            for (int off = 1; off < 64; off <<= 1) {
                float t1 = __shfl_up(pe, off), t2 = __shfl_up(ps, off);
                if (lane >= off) { pe += t1; ps += t2; }
            }
            float E = pe - se, P = ps - ss;   // exclusive prefixes
            for (int i = 0; i < 16; ++i) {
                int l = base + i;
                E += eb[l]; P += sb[l];
                float t = (float)(l + 1);
                float s1 = g1[l], sh = gh[l];
                float a = sh / (E + 1e-12f);
                float b = (s1 - sh) / t;
                float gm = -((b * P + sh) / t);
                al_[h*SEQ + l] = a;
                be_[h*SEQ + l] = b;
                ga_[h*SEQ + l] = gm;
            }
        }
    }
    grid.sync();

    // ================= P3: attention + LayerNorm (768 tasks, <=2 per block) =====
    for (int rep = 0; rep < 2; ++rep) {
        int task = bid + rep*NBLK;
        if (task < 768) {
            int t = task & 63, h = task >> 6;
            short* P  = (short*)smem;                 // [4][16*64]
            float* Op = (float*)(smem + 8192);        // [4][16][64]
            short* Pw = P + wv*1024;
            int m0 = t*16;
            const short* qrow = (const short*)Qb + ((size_t)h*SEQ + m0 + n)*HD + g*8;
            bf16x8 qa0 = *(const bf16x8*)qrow;
            bf16x8 qa1 = *(const bf16x8*)(qrow + 32);
            const float* al = al_ + h*SEQ;
            const float* be = be_ + h*SEQ;
            const float* ga = ga_ + h*SEQ;
            const float* es = es_ + h*SEQ;
            const float* si = si_ + h*SEQ;
            float A_[4], B_[4], G_[4];
            for (int r = 0; r < 4; ++r) {
                int m = m0 + g*4 + r;
                A_[r] = al[m]; B_[r] = be[m]; G_[r] = ga[m];
            }
            f32x4 acco[4];
            for (int et = 0; et < 4; ++et) acco[et] = (f32x4){0.f,0.f,0.f,0.f};

            int jtmax = t >> 2;
            for (int jt = wv; jt <= jtmax; jt += 4) {
                int j0 = jt*64;
                for (int ct = 0; ct < 4; ++ct) {
                    const short* krow = (const short*)Kb + ((size_t)h*SEQ + j0 + ct*16 + n)*HD + g*8;
                    bf16x8 kb0 = *(const bf16x8*)krow;
                    bf16x8 kb1 = *(const bf16x8*)(krow + 32);
                    f32x4 sacc = {0.f,0.f,0.f,0.f};
                    sacc = __builtin_amdgcn_mfma_f32_16x16x32_bf16(qa0, kb0, sacc, 0, 0, 0);
                    sacc = __builtin_amdgcn_mfma_f32_16x16x32_bf16(qa1, kb1, sacc, 0, 0, 0);
                    int j = j0 + ct*16 + n;
                    float ej = es[j], sj = si[j];
                    int chunk = ct*2 + (n>>3), e = n&7;
                    for (int r = 0; r < 4; ++r) {
                        int m = m0 + g*4 + r;
                        float w = (j <= m) ? (A_[r]*ej + B_[r]*sj + G_[r]) : 0.f;
                        int ml = g*4 + r;
                        Pw[ml*64 + (chunk ^ (ml&7))*8 + e] = f2bs(w * sacc[r]);
                    }
                }
                const short* vb = (const short*)Vt + (size_t)h*HD*SEQ;
                for (int et = 0; et < 4; ++et) {
                    for (int sub = 0; sub < 2; ++sub) {
                        int q = sub*4 + g;
                        bf16x8 pa = *(const bf16x8*)(&Pw[n*64 + (q ^ (n&7))*8]);
                        bf16x8 vfr = *(const bf16x8*)(vb + (size_t)(et*16 + n)*SEQ + j0 + sub*32 + g*8);
                        acco[et] = __builtin_amdgcn_mfma_f32_16x16x32_bf16(pa, vfr, acco[et], 0, 0, 0);
                    }
                }
            }
            for (int et = 0; et < 4; ++et)
                for (int r = 0; r < 4; ++r)
                    Op[(wv*16 + g*4 + r)*64 + et*16 + n] = acco[et][r];
            __syncthreads();
            for (int rr = 0; rr < 4; ++rr) {
                int row = wv*4 + rr;
                float v = Op[row*64 + lane] + Op[(16 + row)*64 + lane]
                        + Op[(32 + row)*64 + lane] + Op[(48 + row)*64 + lane];
                float sm = wave_reduce_sum(v);
                float sq = wave_reduce_sum(v*v);
                float mu = sm * (1.f/64.f);
                float var = fmaxf(sq * (1.f/64.f) - mu*mu, 0.f);
                float invs = rsqrtf(var + 1e-5f);
                opre[(size_t)(m0 + row)*DIM + h*HD + lane] = __float2bfloat16((v - mu) * invs);
            }
            __syncthreads();   // protect Op/P reuse by next rep
        }
    }
    grid.sync();

    // ================= P4: output projection (192 tasks) =================
    if (bid < 192) {
        int rt = bid / 12, ct = bid % 12;
        short* lds = (short*)smem;   // A dbuf @0/4096, B dbuf @8192/12288
        int wm = wv>>1, wn = wv&1;
        const short* A = (const short*)opre;

        auto dma_step = [&](int buf, int k0) {
            short* Ab = lds + buf*4096;
            short* Bb = lds + 8192 + buf*4096;
            for (int p = 0; p < 2; ++p) {
                int sbase = p*256 + wv*64;
                int s = sbase + lane;
                int r = s >> 3, c = s & 7, cl = c ^ (r & 7);
                async_copy16(A + (size_t)(rt*64 + r)*DIM + k0 + cl*8, Ab + sbase*8, lane);
                async_copy16(Wob + (size_t)(ct*64 + r)*DIM + k0 + cl*8, Bb + sbase*8, lane);
            }
        };

        f32x4 acc[2][2];
        for (int i=0;i<2;++i) for (int j=0;j<2;++j) acc[i][j] = (f32x4){0,0,0,0};

        dma_step(0, 0);
        for (int it = 0; it < 12; ++it) {
            __syncthreads();
            if (it < 11) dma_step(1 - (it & 1), (it + 1)*64);
            int buf = it & 1;
            const short* Ab = lds + buf*4096;
            const short* Bb = lds + 8192 + buf*4096;
            for (int ks = 0; ks < 2; ++ks) {
                int q = ks*4 + g;
                bf16x8 af[2], bfr[2];
                for (int i=0;i<2;++i)
                    af[i] = *(const bf16x8*)(&Ab[((wm*32+i*16+n)*8 + (q ^ (n&7)))*8]);
                for (int j=0;j<2;++j)
                    bfr[j] = *(const bf16x8*)(&Bb[((wn*32+j*16+n)*8 + (q ^ (n&7)))*8]);
                for (int i=0;i<2;++i)
                    for (int j=0;j<2;++j)
                        acc[i][j] = __builtin_amdgcn_mfma_f32_16x16x32_bf16(af[i], bfr[j], acc[i][j], 0,0,0);
            }
        }
        for (int i=0;i<2;++i) for (int j=0;j<2;++j) for (int r=0;r<4;++r) {
            int row = rt*64 + wm*32 + i*16 + g*4 + r;
            int col = ct*64 + wn*32 + j*16 + n;
            out[(size_t)row*DIM + col] = acc[i][j][r];
        }
    }
}

extern "C" void kernel_launch(void* const* d_in, const int* in_sizes, int n_in,
                              void* d_out, int out_size, void* d_ws, size_t ws_size,
                              hipStream_t stream) {
    const float* X   = (const float*)d_in[0];
    const float* Wq  = (const float*)d_in[1];
    const float* Wk  = (const float*)d_in[2];
    const float* Wv  = (const float*)d_in[3];
    const float* Wu  = (const float*)d_in[4];
    const float* Wg  = (const float*)d_in[5];
    const float* Wo  = (const float*)d_in[6];
    const float* pmu = (const float*)d_in[7];
    const float* plt = (const float*)d_in[8];
    char* ws = (char*)d_ws;
    void* dout = d_out;

    void* args[] = { (void*)&X, (void*)&Wq, (void*)&Wk, (void*)&Wv, (void*)&Wu,
                     (void*)&Wg, (void*)&Wo, (void*)&pmu, (void*)&plt,
                     (void*)&ws, (void*)&dout };
    hipLaunchCooperativeKernel((const void*)k_fused, dim3(NBLK), dim3(256),
                               args, 0, stream);
}

// Round 10
// 170.338 us; speedup vs baseline: 2.6619x; 2.6619x over previous
//
#include <hip/hip_runtime.h>
#include <hip/hip_bf16.h>
#include <math.h>

typedef __attribute__((ext_vector_type(8))) short bf16x8;
typedef __attribute__((ext_vector_type(4))) float f32x4;

#define SEQ 1024
#define DIM 768
#define NH 12
#define HD 64

// ws layout (BYTE offsets):
//   Qb   bf16 [12][1024][64]  @ 0
//   Kb   bf16 [12][1024][64]  @ 1572864
//   Vt   bf16 [768][1024]     @ 3145728   (v transposed: [h*64+e][l])
//   opre bf16 [1024][768]     @ 4718592
//   G    f32  [1024][36]      @ 6291456
//   scal f32  5*[12][1024]    @ 6438912   (si, es, al, be, ga)
//   Xb   bf16 [1024][768]     @ 6684672   (pre-cast inputs for DMA staging)
//   Wqb  bf16 [768][768]      @ 8257536
//   Wkb  bf16 [768][768]      @ 9437184
//   Wvb  bf16 [768][768]      @ 10616832
//   Wub  bf16 [768][768]      @ 11796480
//   Wgb  bf16 [36][768]       @ 12976128
//   Wob  bf16 [768][768]      @ 13031424
// u (bf16 [12][1024][64]) borrows d_out as scratch; k_oproj overwrites it last.
// NOTE (R9 post-mortem): grid.sync() costs ~50 µs on MI355X (cross-XCD barrier)
// — stream-ordered kernel boundaries are the cheap grid barrier. Never fuse
// phases with cooperative sync here.

__device__ __forceinline__ float wave_reduce_sum(float v) {
    for (int off = 1; off < 64; off <<= 1) v += __shfl_xor(v, off);
    return v;
}
__device__ __forceinline__ short f2bs(float x) {
    __hip_bfloat16 h = __float2bfloat16(x);
    return *reinterpret_cast<short*>(&h);
}
__device__ __forceinline__ float bs2f(short x) {
    __hip_bfloat16 h = *reinterpret_cast<__hip_bfloat16*>(&x);
    return (float)h;
}
__device__ __forceinline__ bf16x8 cvt8r(const float4& a, const float4& b) {
    bf16x8 r;
    r[0]=f2bs(a.x); r[1]=f2bs(a.y); r[2]=f2bs(a.z); r[3]=f2bs(a.w);
    r[4]=f2bs(b.x); r[5]=f2bs(b.y); r[6]=f2bs(b.z); r[7]=f2bs(b.w);
    return r;
}
__device__ __forceinline__ void async_copy16(const void* gptr, void* ldsbase, int lane) {
#if __has_builtin(__builtin_amdgcn_global_load_lds)
    __builtin_amdgcn_global_load_lds(
        (const __attribute__((address_space(1))) unsigned int*)gptr,
        (__attribute__((address_space(3))) unsigned int*)ldsbase, 16, 0, 0);
#else
    *(bf16x8*)((short*)ldsbase + lane*8) = *(const bf16x8*)gptr;
#endif
}

// ---------------- K0: pre-cast X + weights to bf16 (one pass, BW-bound) -------
__global__ __launch_bounds__(256) void k_prep(const float* __restrict__ X,
    const float* __restrict__ Wq, const float* __restrict__ Wk,
    const float* __restrict__ Wv, const float* __restrict__ Wu,
    const float* __restrict__ Wg, const float* __restrict__ Wo,
    short* __restrict__ Xb, short* __restrict__ Wqb, short* __restrict__ Wkb,
    short* __restrict__ Wvb, short* __restrict__ Wub, short* __restrict__ Wgb,
    short* __restrict__ Wob)
{
    int seg = blockIdx.y;
    const float* src; short* dst; int n8;
    switch (seg) {
        case 0: src = X;  dst = Xb;  n8 = 98304; break;
        case 1: src = Wq; dst = Wqb; n8 = 73728; break;
        case 2: src = Wk; dst = Wkb; n8 = 73728; break;
        case 3: src = Wv; dst = Wvb; n8 = 73728; break;
        case 4: src = Wu; dst = Wub; n8 = 73728; break;
        case 5: src = Wg; dst = Wgb; n8 = 3456;  break;
        default: src = Wo; dst = Wob; n8 = 73728; break;
    }
    int i = blockIdx.x*256 + threadIdx.x;
    if (i >= n8) return;
    const float* s = src + (size_t)i*8;
    *(bf16x8*)(dst + (size_t)i*8) = cvt8r(*(const float4*)s, *(const float4*)(s + 4));
}

// ---------------- K1: 5 projections, 64x128 dbuf GEMM, global_load_lds staging
// Task-packed 1D grid: exactly 400 live blocks (no early-return waste).
// mat: 0=q 1=k 2=v(A/B swapped -> V^T row-contiguous) 3=u 4=gate.
__global__ __launch_bounds__(256, 3) void k_proj5(const short* __restrict__ Xb,
    const short* __restrict__ Wqb, const short* __restrict__ Wkb,
    const short* __restrict__ Wvb, const short* __restrict__ Wub,
    const short* __restrict__ Wgb,
    __hip_bfloat16* __restrict__ Qb, __hip_bfloat16* __restrict__ Kb,
    __hip_bfloat16* __restrict__ Vt, __hip_bfloat16* __restrict__ Ub,
    float* __restrict__ G)
{
    int t = blockIdx.x;
    int mat, rt, ct;
    if (t < 288)      { int m3 = t/96; mat = (m3==2)?3:m3; int r = t%96; rt = r/6; ct = r%6; }
    else if (t < 384) { mat = 2; int r = t-288; rt = r/8; ct = r%8; }
    else              { mat = 4; rt = t-384; ct = 0; }

    __shared__ short lds[24576];   // A dbuf @0/4096 (64x64), B dbuf @8192/16384 (128x64)

    int tid = threadIdx.x;
    int wv = tid>>6, lane = tid&63, g = lane>>4, n = lane&15;
    int wn = wv;                                       // wave owns 32 cols of 128

    const short* Asrc; const short* Bsrc; int arow0, brow0, Brows;
    if (mat == 2) { Asrc = Wvb; Bsrc = Xb; arow0 = rt*64; brow0 = ct*128; Brows = SEQ; }
    else {
        Asrc = Xb; arow0 = rt*64; brow0 = ct*128;
        Bsrc = (mat==0)?Wqb:(mat==1)?Wkb:(mat==3)?Wub:Wgb;
        Brows = (mat==4) ? 36 : DIM;
    }

    auto dma_step = [&](int buf, int k0) {
        short* Ab = lds + buf*4096;
        short* Bb = lds + 8192 + buf*8192;
        for (int p = 0; p < 2; ++p) {                  // A: 64 rows x 8 chunks
            int sbase = p*256 + wv*64;
            int s = sbase + lane;
            int r = s >> 3, c = s & 7, cl = c ^ (r & 7);
            async_copy16(Asrc + (size_t)(arow0 + r)*DIM + k0 + cl*8, Ab + sbase*8, lane);
        }
        for (int p = 0; p < 4; ++p) {                  // B: 128 rows x 8 chunks
            int sbase = p*256 + wv*64;
            int s = sbase + lane;
            int r = s >> 3, c = s & 7, cl = c ^ (r & 7);
            int gr = brow0 + r; if (gr >= Brows) gr = Brows - 1;   // gate clamp
            async_copy16(Bsrc + (size_t)gr*DIM + k0 + cl*8, Bb + sbase*8, lane);
        }
    };

    f32x4 acc[4][2];
    for (int i=0;i<4;++i) for (int j=0;j<2;++j) acc[i][j] = (f32x4){0,0,0,0};

    dma_step(0, 0);
    for (int it = 0; it < 12; ++it) {
        __syncthreads();                                // drains DMA for buf it&1
        if (it < 11) dma_step(1 - (it & 1), (it + 1)*64);
        int buf = it & 1;
        const short* Ab = lds + buf*4096;
        const short* Bb = lds + 8192 + buf*8192;
        for (int ks = 0; ks < 2; ++ks) {
            int q = ks*4 + g;
            bf16x8 af[4], bfr[2];
            for (int i=0;i<4;++i)
                af[i] = *(const bf16x8*)(&Ab[((i*16+n)*8 + (q ^ (n&7)))*8]);
            for (int j=0;j<2;++j)
                bfr[j] = *(const bf16x8*)(&Bb[((wn*32+j*16+n)*8 + (q ^ (n&7)))*8]);
            for (int i=0;i<4;++i)
                for (int j=0;j<2;++j)
                    acc[i][j] = __builtin_amdgcn_mfma_f32_16x16x32_bf16(af[i], bfr[j], acc[i][j], 0,0,0);
        }
    }
    __syncthreads();

    // ---- gate: tiny, direct f32 writes ----
    if (mat == 4) {
        for (int i=0;i<4;++i) for (int j=0;j<2;++j) for (int r=0;r<4;++r) {
            int row = rt*64 + i*16 + g*4 + r;
            int col = wn*32 + j*16 + n;
            if (col < 36) G[(size_t)row*36 + col] = acc[i][j][r];
        }
        return;
    }

    // ---- stage C tile bf16 [64 rows][128 cols] in LDS (reuses A buffers) ----
    short* C = lds;
    for (int i=0;i<4;++i) for (int j=0;j<2;++j) for (int r=0;r<4;++r)
        C[(i*16 + g*4 + r)*128 + wn*32 + j*16 + n] = f2bs(acc[i][j][r]);
    __syncthreads();

    if (mat == 2) {
        // C[e_local][l_local] -> Vt[e][l], 256B runs via uint
        for (int k = 0; k < 16; ++k) {
            int row = k*4 + wv;
            unsigned int v = ((const unsigned int*)C)[row*64 + lane];
            ((unsigned int*)(Vt + (size_t)(rt*64 + row)*SEQ + ct*128))[lane] = v;
        }
    } else if (mat == 3) {
        for (int k = 0; k < 32; ++k) {
            int u = k*4 + wv;             // 0..127 row-head pairs
            int row = u >> 1, hsel = u & 1;
            Ub[((size_t)(2*ct + hsel)*SEQ + rt*64 + row)*HD + lane] =
                *(__hip_bfloat16*)&C[row*128 + hsel*64 + lane];
        }
    } else {
        // q/k: fused RoPE + L2 normalize, head-major write
        __hip_bfloat16* dst = (mat==0) ? Qb : Kb;
        int i2 = lane >> 1;
        float inv = expf((float)i2 * (-9.210340371976184f / 32.f));  // 10000^{-i2/32}
        for (int k = 0; k < 32; ++k) {
            int u = k*4 + wv;
            int row = u >> 1, hsel = u & 1;
            int l = rt*64 + row;
            float x = bs2f(C[row*128 + hsel*64 + lane]);
            float ang = (float)l * inv;
            float c = cosf(ang), s = sinf(ang);
            float p = __shfl(x, lane ^ 32);
            float rot = (lane < 32) ? -p : p;
            float y = x*c + rot*s;
            float nrm = wave_reduce_sum(y*y);
            y = y / fmaxf(sqrtf(nrm), 1e-12f);
            dst[((size_t)(2*ct + hsel)*SEQ + l)*HD + lane] = __float2bfloat16(y);
        }
    }
}

// ---------------- K2: per-head cumsum(u) -> s_i, smax, E/P scans -> alpha/beta/gamma
__global__ __launch_bounds__(1024) void k_scan(const __hip_bfloat16* __restrict__ Ub,
    const float* __restrict__ G, const float* __restrict__ pmu,
    const float* __restrict__ plt,
    float* __restrict__ si_, float* __restrict__ es_, float* __restrict__ al_,
    float* __restrict__ be_, float* __restrict__ ga_)
{
    int h = blockIdx.x;
    int tid = threadIdx.x, wv = tid >> 6, lane = tid & 63;
    __shared__ float sbuf[SEQ], ebuf[SEQ], g1b[SEQ], ghb[SEQ];
    __shared__ float stot[16][64];
    __shared__ float wmax[16];
    __shared__ float smax_s;

    float ltv = fminf(fmaxf(plt[h], -50.f), 30.f);
    float ltau = expf(ltv);
    float mu = pmu[h*HD + lane];

    const __hip_bfloat16* up = Ub + ((size_t)h*SEQ + wv*64)*HD + lane;
    float Ul = 0.f;
    for (int i = 0; i < 64; ++i) Ul += (float)up[(size_t)i*HD];
    stot[wv][lane] = Ul;
    __syncthreads();
    float pre = ltau * mu;
    for (int w2 = 0; w2 < wv; ++w2) pre += stot[w2][lane];
    float V = pre;
    for (int i = 0; i < 64; ++i) {
        float uv = (float)up[(size_t)i*HD];
        V += uv;
        int l = wv*64 + i;
        float bar = V / (ltau + (float)(l + 1));
        float p = wave_reduce_sum(uv * bar);
        if (lane == 0) sbuf[l] = -p * 0.125f;   // / sqrt(64)
    }
    __syncthreads();
    float v = sbuf[tid];
    float vm = v;
    for (int off = 1; off < 64; off <<= 1) vm = fmaxf(vm, __shfl_xor(vm, off));
    if (lane == 0) wmax[wv] = vm;
    __syncthreads();
    if (wv == 0) {
        float mm = (lane < 16) ? wmax[lane] : -1e30f;
        for (int off = 1; off < 16; off <<= 1) mm = fmaxf(mm, __shfl_xor(mm, off));
        if (lane == 0) smax_s = mm;
    }
    __syncthreads();
    float ev = expf(fminf(v - smax_s, 0.f));
    ebuf[tid] = ev;
    g1b[tid] = 1.f / (1.f + expf(-G[(size_t)tid*36 + h*3 + 0]));
    ghb[tid] = 1.f / (1.f + expf(-G[(size_t)tid*36 + h*3 + 1]));
    si_[h*SEQ + tid] = v;
    es_[h*SEQ + tid] = ev;
    __syncthreads();
    if (wv == 0) {
        int base = lane * 16;
        float se = 0.f, ss = 0.f;
        for (int i = 0; i < 16; ++i) { se += ebuf[base + i]; ss += sbuf[base + i]; }
        float pe = se, ps = ss;
        for (int off = 1; off < 64; off <<= 1) {
            float t1 = __shfl_up(pe, off), t2 = __shfl_up(ps, off);
            if (lane >= off) { pe += t1; ps += t2; }
        }
        float E = pe - se, P = ps - ss;   // exclusive prefixes
        for (int i = 0; i < 16; ++i) {
            int l = base + i;
            E += ebuf[l]; P += sbuf[l];
            float t = (float)(l + 1);
            float s1 = g1b[l], sh = ghb[l];
            float a = sh / (E + 1e-12f);
            float b = (s1 - sh) / t;
            float gm = -((b * P + sh) / t);
            al_[h*SEQ + l] = a;
            be_[h*SEQ + l] = b;
            ga_[h*SEQ + l] = gm;
        }
    }
}

// ---------------- K4: causal weighted linear attention + LayerNorm -------------
__global__ __launch_bounds__(256) void k_attn(const __hip_bfloat16* __restrict__ Qb,
    const __hip_bfloat16* __restrict__ Kb, const __hip_bfloat16* __restrict__ Vt,
    const float* __restrict__ si_, const float* __restrict__ es_,
    const float* __restrict__ al_, const float* __restrict__ be_,
    const float* __restrict__ ga_, __hip_bfloat16* __restrict__ opre)
{
    int t = blockIdx.x, h = blockIdx.y;   // q-tile 0..63
    int wv = threadIdx.x >> 6, lane = threadIdx.x & 63;
    int g = lane >> 4, n = lane & 15;
    __shared__ short P[4][16*64];
    __shared__ float Op[4][16][64];
    short* Pw = P[wv];
    int m0 = t*16;
    const short* qrow = (const short*)Qb + ((size_t)h*SEQ + m0 + n)*HD + g*8;
    bf16x8 qa0 = *(const bf16x8*)qrow;
    bf16x8 qa1 = *(const bf16x8*)(qrow + 32);
    const float* al = al_ + h*SEQ;
    const float* be = be_ + h*SEQ;
    const float* ga = ga_ + h*SEQ;
    const float* es = es_ + h*SEQ;
    const float* si = si_ + h*SEQ;
    float A_[4], B_[4], G_[4];
    for (int r = 0; r < 4; ++r) {
        int m = m0 + g*4 + r;
        A_[r] = al[m]; B_[r] = be[m]; G_[r] = ga[m];
    }
    f32x4 acco[4];
    for (int et = 0; et < 4; ++et) acco[et] = (f32x4){0.f,0.f,0.f,0.f};

    int jtmax = t >> 2;
    for (int jt = wv; jt <= jtmax; jt += 4) {
        int j0 = jt*64;
        for (int ct = 0; ct < 4; ++ct) {
            const short* krow = (const short*)Kb + ((size_t)h*SEQ + j0 + ct*16 + n)*HD + g*8;
            bf16x8 kb0 = *(const bf16x8*)krow;
            bf16x8 kb1 = *(const bf16x8*)(krow + 32);
            f32x4 sacc = {0.f,0.f,0.f,0.f};
            sacc = __builtin_amdgcn_mfma_f32_16x16x32_bf16(qa0, kb0, sacc, 0, 0, 0);
            sacc = __builtin_amdgcn_mfma_f32_16x16x32_bf16(qa1, kb1, sacc, 0, 0, 0);
            int j = j0 + ct*16 + n;
            float ej = es[j], sj = si[j];
            int chunk = ct*2 + (n>>3), e = n&7;
            for (int r = 0; r < 4; ++r) {
                int m = m0 + g*4 + r;
                float w = (j <= m) ? (A_[r]*ej + B_[r]*sj + G_[r]) : 0.f;
                int ml = g*4 + r;
                Pw[ml*64 + (chunk ^ (ml&7))*8 + e] = f2bs(w * sacc[r]);
            }
        }
        const short* vb = (const short*)Vt + (size_t)h*HD*SEQ;
        for (int et = 0; et < 4; ++et) {
            for (int sub = 0; sub < 2; ++sub) {
                int q = sub*4 + g;
                bf16x8 pa = *(const bf16x8*)(&Pw[n*64 + (q ^ (n&7))*8]);
                bf16x8 vfr = *(const bf16x8*)(vb + (size_t)(et*16 + n)*SEQ + j0 + sub*32 + g*8);
                acco[et] = __builtin_amdgcn_mfma_f32_16x16x32_bf16(pa, vfr, acco[et], 0, 0, 0);
            }
        }
    }
    for (int et = 0; et < 4; ++et)
        for (int r = 0; r < 4; ++r)
            Op[wv][g*4 + r][et*16 + n] = acco[et][r];
    __syncthreads();
    for (int rr = 0; rr < 4; ++rr) {
        int row = wv*4 + rr;
        float v = Op[0][row][lane] + Op[1][row][lane] + Op[2][row][lane] + Op[3][row][lane];
        float sm = wave_reduce_sum(v);
        float sq = wave_reduce_sum(v*v);
        float mu = sm * (1.f/64.f);
        float var = fmaxf(sq * (1.f/64.f) - mu*mu, 0.f);
        float invs = rsqrtf(var + 1e-5f);
        opre[(size_t)(m0 + row)*DIM + h*HD + lane] = __float2bfloat16((v - mu) * invs);
    }
}

// ---------------- K5: output projection, 64x64 dbuf GEMM, DMA staging, f32 out -
__global__ __launch_bounds__(256, 4) void k_oproj(const short* __restrict__ A,
    const short* __restrict__ Wob, float* __restrict__ out)
{
    int rt = blockIdx.x, ct = blockIdx.y;
    __shared__ short lds[16384];   // A dbuf @0/4096, B dbuf @8192/12288 (64x64)

    int tid = threadIdx.x;
    int wv = tid>>6, lane = tid&63, g = lane>>4, n = lane&15;
    int wm = wv>>1, wn = wv&1;

    auto dma_step = [&](int buf, int k0) {
        short* Ab = lds + buf*4096;
        short* Bb = lds + 8192 + buf*4096;
        for (int p = 0; p < 2; ++p) {
            int sbase = p*256 + wv*64;
            int s = sbase + lane;
            int r = s >> 3, c = s & 7, cl = c ^ (r & 7);
            async_copy16(A + (size_t)(rt*64 + r)*DIM + k0 + cl*8, Ab + sbase*8, lane);
            async_copy16(Wob + (size_t)(ct*64 + r)*DIM + k0 + cl*8, Bb + sbase*8, lane);
        }
    };

    f32x4 acc[2][2];
    for (int i=0;i<2;++i) for (int j=0;j<2;++j) acc[i][j] = (f32x4){0,0,0,0};

    dma_step(0, 0);
    for (int it = 0; it < 12; ++it) {
        __syncthreads();
        if (it < 11) dma_step(1 - (it & 1), (it + 1)*64);
        int buf = it & 1;
        const short* Ab = lds + buf*4096;
        const short* Bb = lds + 8192 + buf*4096;
        for (int ks = 0; ks < 2; ++ks) {
            int q = ks*4 + g;
            bf16x8 af[2], bfr[2];
            for (int i=0;i<2;++i)
                af[i] = *(const bf16x8*)(&Ab[((wm*32+i*16+n)*8 + (q ^ (n&7)))*8]);
            for (int j=0;j<2;++j)
                bfr[j] = *(const bf16x8*)(&Bb[((wn*32+j*16+n)*8 + (q ^ (n&7)))*8]);
            for (int i=0;i<2;++i)
                for (int j=0;j<2;++j)
                    acc[i][j] = __builtin_amdgcn_mfma_f32_16x16x32_bf16(af[i], bfr[j], acc[i][j], 0,0,0);
        }
    }
    for (int i=0;i<2;++i) for (int j=0;j<2;++j) for (int r=0;r<4;++r) {
        int row = rt*64 + wm*32 + i*16 + g*4 + r;
        int col = ct*64 + wn*32 + j*16 + n;
        out[(size_t)row*DIM + col] = acc[i][j][r];
    }
}

extern "C" void kernel_launch(void* const* d_in, const int* in_sizes, int n_in,
                              void* d_out, int out_size, void* d_ws, size_t ws_size,
                              hipStream_t stream) {
    const float* X   = (const float*)d_in[0];
    const float* Wq  = (const float*)d_in[1];
    const float* Wk  = (const float*)d_in[2];
    const float* Wv  = (const float*)d_in[3];
    const float* Wu  = (const float*)d_in[4];
    const float* Wg  = (const float*)d_in[5];
    const float* Wo  = (const float*)d_in[6];
    const float* pmu = (const float*)d_in[7];
    const float* plt = (const float*)d_in[8];

    char* w = (char*)d_ws;
    __hip_bfloat16* Qb   = (__hip_bfloat16*)(w + 0);
    __hip_bfloat16* Kb   = (__hip_bfloat16*)(w + 1572864);
    __hip_bfloat16* Vt   = (__hip_bfloat16*)(w + 3145728);
    __hip_bfloat16* opre = (__hip_bfloat16*)(w + 4718592);
    float*          G    = (float*)(w + 6291456);
    float*          si_  = (float*)(w + 6438912);
    float*          es_  = si_ + NH*SEQ;
    float*          al_  = es_ + NH*SEQ;
    float*          be_  = al_ + NH*SEQ;
    float*          ga_  = be_ + NH*SEQ;
    short*          Xb   = (short*)(w + 6684672);
    short*          Wqb  = (short*)(w + 8257536);
    short*          Wkb  = (short*)(w + 9437184);
    short*          Wvb  = (short*)(w + 10616832);
    short*          Wub  = (short*)(w + 11796480);
    short*          Wgb  = (short*)(w + 12976128);
    short*          Wob  = (short*)(w + 13031424);
    __hip_bfloat16* Ub   = (__hip_bfloat16*)d_out;   // scratch; k_oproj overwrites last
    float*          out  = (float*)d_out;

    hipLaunchKernelGGL(k_prep, dim3(384, 7), dim3(256), 0, stream,
                       X, Wq, Wk, Wv, Wu, Wg, Wo, Xb, Wqb, Wkb, Wvb, Wub, Wgb, Wob);
    hipLaunchKernelGGL(k_proj5, dim3(400), dim3(256), 0, stream,
                       Xb, Wqb, Wkb, Wvb, Wub, Wgb, Qb, Kb, Vt, Ub, G);
    hipLaunchKernelGGL(k_scan, dim3(NH), dim3(1024), 0, stream,
                       Ub, G, pmu, plt, si_, es_, al_, be_, ga_);
    hipLaunchKernelGGL(k_attn, dim3(64, NH), dim3(256), 0, stream,
                       Qb, Kb, Vt, si_, es_, al_, be_, ga_, opre);
    hipLaunchKernelGGL(k_oproj, dim3(16, 12), dim3(256), 0, stream,
                       (const short*)opre, Wob, out);
}